// Round 1
// 270.728 us; speedup vs baseline: 1.1895x; 1.1895x over previous
//
#include <hip/hip_runtime.h>

// LSTM: B=2048, T=512, I=6, H=50, O=3. fp32 in/out, bf16 MFMA inner matmul.
//
// R4: latency-chain restructure. Old: NB=4, grid=512, 2 WGs/CU -> per-step
// wall 1240 cyc while issue work was ~300/SIMD (co-WG contention + 4-wave
// barrier straggle + per-step x-feed on wave 3). New: NB=8, grid=256 =
// 1 WG/CU (no co-resident WG), 512 thr = 8 waves. MFMA cols now 8/16 used
// (was 4/16): same 26 MFMA/WG/step, half the WGs -> half chip MFMA work.
//
// k'-permutation kills the per-step x copy: k' 0..47,56,57 = h(0..49);
// k' 48..55 = [x(0..5), bias(1.0), 0] read by quad-2 lanes directly from
// prepacked bf16 Xpack[t][b] (built once, 64 KB LDS). No global loads and
// no x staging inside the step loop (lgkm-only drain at the barrier).
//
// Wave-private gate scratch: wave w owns tiles {w, w+8} -> h-indices
// 4w+quad, 32+4w+quad -> exactly 64 (b,hh) pairs = its own 64 lanes.
// Writer slot = 32*ti + 8*quad + col (conflict-free per 16-lane phase),
// reader slot = lane. Same-wave LDS in-order: no extra barrier.
// 1 barrier/step; c-state in registers; <=1 (b,hh) pair per lane.

#define L2E 1.44269504088896340736f

typedef float  f32x4  __attribute__((ext_vector_type(4)));
typedef short  s16x8  __attribute__((ext_vector_type(8)));   // 8 bf16 bit-patterns

__device__ __forceinline__ float fast_exp2(float x){ return __builtin_amdgcn_exp2f(x); }
__device__ __forceinline__ float fast_rcp (float x){ return __builtin_amdgcn_rcpf(x); }
__device__ __forceinline__ float sigm (float x){ return fast_rcp(1.0f + fast_exp2(-L2E * x)); }
__device__ __forceinline__ float tanhf_(float x){ return 1.0f - 2.0f * fast_rcp(1.0f + fast_exp2((2.0f*L2E) * x)); }

// float -> bf16 bits, round-to-nearest-even
__device__ __forceinline__ unsigned short f2bf(float f){
  unsigned u = __builtin_bit_cast(unsigned, f);
  u = (u + 0x7FFFu + ((u >> 16) & 1u)) >> 16;
  return (unsigned short)u;
}

constexpr int B_ = 2048, T_ = 512, I_ = 6, H_ = 50;
constexpr int NB = 8;       // batch rows per WG  (grid = 256 = 1 WG/CU)
constexpr int AP = 72;      // Abuf row pitch in bf16 elems (144 B, 2-way free)
constexpr int T6 = T_ * I_; // floats per batch row of x

__global__ __launch_bounds__(512, 1)
void lstm_kernel(const float* __restrict__ x,
                 const float* __restrict__ W_ih, const float* __restrict__ W_hh,
                 const float* __restrict__ b_ih, const float* __restrict__ b_hh,
                 const float* __restrict__ W_out, const float* __restrict__ b_out,
                 float* __restrict__ out)
{
  __shared__ unsigned short Xpack[T_][NB][8];  // 64 KB: [x0..x5, 1.0, 0] bf16 per (t,b)
  __shared__ unsigned short Abuf[2][16 * AP];  // 4.6 KB: h at pos 0..47,56,57; rest 0
  __shared__ float Gs[8][64][4];               // 8 KB: wave-private merged-gate scratch
  __shared__ float Hlast[NB][H_];

  const int tid  = threadIdx.x;
  const int lane = tid & 63;
  const int wave = tid >> 6;
  const int col  = lane & 15;   // MFMA N index = batch row
  const int quad = lane >> 4;   // MFMA k-slice group
  const int b0   = blockIdx.x * NB;

  // ---- stage Xpack: thread tid handles (t=tid, b=i); consecutive tids read
  // consecutive 24 B chunks of row b0+i (coalesced). One-time, 96 KB in. ----
  #pragma unroll
  for (int i = 0; i < NB; i++) {
    const float* xp = x + (size_t)(b0 + i) * T6 + tid * I_;
    const float2 a0 = *(const float2*)(xp);
    const float2 a1 = *(const float2*)(xp + 2);
    const float2 a2 = *(const float2*)(xp + 4);
    unsigned* dst = (unsigned*)&Xpack[tid][i][0];
    dst[0] = (unsigned)f2bf(a0.x) | ((unsigned)f2bf(a0.y) << 16);
    dst[1] = (unsigned)f2bf(a1.x) | ((unsigned)f2bf(a1.y) << 16);
    dst[2] = (unsigned)f2bf(a2.x) | ((unsigned)f2bf(a2.y) << 16);
    dst[3] = 0x3F80u;            // [bias=1.0, 0]
  }

  // ---- zero Abuf (h(0)=0; pads stay 0 forever) ----
  for (int i = tid; i < 2 * 16 * AP; i += 512) (&Abuf[0][0])[i] = 0;

  // ---- load weight fragments (A-operand, once) ----
  // wave w owns tiles jt in {w, w+8} (jt<13). lane holds W' row jp = jt*16+col,
  // k'-slice quad*8..+7 (+32 for kh=1). jp = 4*hidx+gate -> src row = gate*50+hidx.
  // k' map: 0..47 -> W_hh[.][k'], 48..53 -> W_ih[.][k'-48], 54 -> bias,
  //         56,57 -> W_hh[.][48,49], else 0.
  const int ntw = (wave < 5) ? 2 : 1;   // tiles 0..12
  s16x8 wf[2][2];
  #pragma unroll
  for (int ti = 0; ti < 2; ti++) {
    if (ti < ntw) {
      const int jp = (wave + 8 * ti) * 16 + col;
      const bool ok = jp < 200;
      const int hidx = jp >> 2, g = jp & 3;
      const int row = g * 50 + hidx;
      #pragma unroll
      for (int kh = 0; kh < 2; kh++) {
        s16x8 w;
        #pragma unroll
        for (int kk = 0; kk < 8; kk++) {
          const int k = kh * 32 + quad * 8 + kk;
          float v = 0.0f;
          if (ok) {
            if      (k < 48)  v = W_hh[row * 50 + k];
            else if (k < 54)  v = W_ih[row * 6 + (k - 48)];
            else if (k == 54) v = b_ih[row] + b_hh[row];
            else if (k == 56) v = W_hh[row * 50 + 48];
            else if (k == 57) v = W_hh[row * 50 + 49];
          }
          w[kk] = (short)f2bf(v);
        }
        wf[ti][kh] = w;
      }
    }
  }

  // ---- merged-lane identity: slot = lane; decodes (ti, quad, b) ----
  const int ti_r   = lane >> 5;
  const int quad_r = (lane >> 3) & 3;
  const int b_r    = lane & 7;
  const int jt_r   = wave + 8 * ti_r;
  const int hh     = 4 * jt_r + quad_r;
  const bool valid = (jt_r < 13) && (hh < H_);
  const int pos    = hh + ((hh >= 48) ? 8 : 0);   // h48,h49 live at 56,57

  float c_ = 0.0f, hreg = 0.0f;

  __syncthreads();

  #pragma unroll 2
  for (int t = 0; t < T_; t++) {
    const unsigned short* Ar = &Abuf[t & 1][0];
    unsigned short*       Aw = &Abuf[(t + 1) & 1][0];

    // B-operand fragments: B[k'][n=batch]. quad2's kh=1 slice is [x|bias|0],
    // read straight from Xpack (no per-step copy). col>=8: garbage cols,
    // results discarded by the col<NB gate below.
    const unsigned short* arow = Ar + col * AP;
    const s16x8 bfr0 = *(const s16x8*)(arow + quad * 8);
    const unsigned short* p1 = (quad == 2) ? &Xpack[t][col & 7][0]
                                           : (arow + 32 + quad * 8);
    const s16x8 bfr1 = *(const s16x8*)p1;

    // MFMA per tile; scatter (i,f,g,o) quads into wave-private slots
    #pragma unroll
    for (int ti = 0; ti < 2; ti++) {
      if (ti < ntw) {
        const int jt = wave + 8 * ti;
        f32x4 a = {0.f, 0.f, 0.f, 0.f};
        a = __builtin_amdgcn_mfma_f32_16x16x32_bf16(wf[ti][0], bfr0, a, 0, 0, 0);
        a = __builtin_amdgcn_mfma_f32_16x16x32_bf16(wf[ti][1], bfr1, a, 0, 0, 0);
        if (col < NB && (4 * jt + quad) < H_)
          *(f32x4*)&Gs[wave][ti * 32 + quad * 8 + col][0] = a;
      }
    }

    // merged read: lane gets (i,f,g,o) of its (b_r, hh) pair.
    // Same-wave LDS ops are in-order: no extra barrier.
    if (valid) {
      const f32x4 g = *(const f32x4*)&Gs[wave][lane][0];
      const float gi = sigm (g[0]);
      const float gf = sigm (g[1]);
      const float gg = tanhf_(g[2]);
      const float go = sigm (g[3]);
      c_ = gf * c_ + gi * gg;
      hreg = go * tanhf_(c_);
      Aw[b_r * AP + pos] = f2bf(hreg);
    }

    __syncthreads();  // Aw visible to all waves; lgkm-only drain (no vmcnt)
  }

  // ---- epilogue: logits + softmax ----
  if (valid) Hlast[b_r][hh] = hreg;
  __syncthreads();

  if (tid < NB) {
    float l[3];
    #pragma unroll
    for (int o = 0; o < 3; o++) {
      float s = b_out[o];
      for (int k = 0; k < H_; k++) s += W_out[o * H_ + k] * Hlast[tid][k];
      l[o] = s;
    }
    const float m  = fmaxf(l[0], fmaxf(l[1], l[2]));
    const float e0 = fast_exp2((l[0] - m) * L2E);
    const float e1 = fast_exp2((l[1] - m) * L2E);
    const float e2 = fast_exp2((l[2] - m) * L2E);
    const float inv = fast_rcp(e0 + e1 + e2);
    float* op = out + (size_t)(b0 + tid) * 3;
    op[0] = e0 * inv; op[1] = e1 * inv; op[2] = e2 * inv;
  }
}

extern "C" void kernel_launch(void* const* d_in, const int* in_sizes, int n_in,
                              void* d_out, int out_size, void* d_ws, size_t ws_size,
                              hipStream_t stream) {
  const float* x     = (const float*)d_in[0];
  const float* W_ih  = (const float*)d_in[1];
  const float* W_hh  = (const float*)d_in[2];
  const float* b_ih  = (const float*)d_in[3];
  const float* b_hh  = (const float*)d_in[4];
  const float* W_out = (const float*)d_in[5];
  const float* b_out = (const float*)d_in[6];
  lstm_kernel<<<B_ / NB, 512, 0, stream>>>(x, W_ih, W_hh, b_ih, b_hh,
                                           W_out, b_out, (float*)d_out);
}

// Round 2
// 242.679 us; speedup vs baseline: 1.3270x; 1.1156x over previous
//
#include <hip/hip_runtime.h>

// LSTM: B=2048, T=512, I=6, H=50, O=3. fp32 in/out, bf16 MFMA inner matmul.
//
// R5: kill the Gs LDS round-trip. With j' = 4*hidx+gate column permutation,
// the MFMA acc ALREADY holds (i,f,g,o) of pair (b=col, hh=4*jt+quad) in its
// 4 regs (reg r = gate r). The old Gs write+read (~240 cyc serial LDS
// latency, 4-way bank conflict both sides) only moved tile-1 pairs from
// cols 0..7 to cols 8..15 -> replaced by __shfl_xor(.,8) on 4 regs
// (DPP/swizzle, no LDS banks). Also: fold L2E into the bf16 weights at
// frag-load (gate g rows get 2*L2E since tanh needs exp2(2*L2E*x)), and
// exp2(-y) uses the free neg modifier -> ~5 fewer VALU muls on the chain.
//
// Structure (from R4): NB=8, grid=256 = 1 WG/CU, 512 thr = 8 waves.
// Wave w owns tiles {w, w+8} (jt<13). k' 0..47,56,57 = h; k' 48..55 =
// [x,bias,0] read by quad-2 lanes straight from prepacked Xpack[t][b]
// (no per-step x copy, lgkm-only drain at the 1 barrier/step).
// Lane pair map: b = col&7, hh = 4*(wave + 8*(col>=8)) + quad.

#define L2E 1.44269504088896340736f

typedef float  f32x4  __attribute__((ext_vector_type(4)));
typedef short  s16x8  __attribute__((ext_vector_type(8)));   // 8 bf16 bit-patterns

__device__ __forceinline__ float fast_exp2(float x){ return __builtin_amdgcn_exp2f(x); }
__device__ __forceinline__ float fast_rcp (float x){ return __builtin_amdgcn_rcpf(x); }
// inputs pre-scaled by L2E (sig) / 2*L2E (tanh):
__device__ __forceinline__ float sigm_p(float y){ return fast_rcp(1.0f + fast_exp2(-y)); }
__device__ __forceinline__ float tanh_p(float y){ return 1.0f - 2.0f * fast_rcp(1.0f + fast_exp2(y)); }

// float -> bf16 bits, round-to-nearest-even
__device__ __forceinline__ unsigned short f2bf(float f){
  unsigned u = __builtin_bit_cast(unsigned, f);
  u = (u + 0x7FFFu + ((u >> 16) & 1u)) >> 16;
  return (unsigned short)u;
}

constexpr int B_ = 2048, T_ = 512, I_ = 6, H_ = 50;
constexpr int NB = 8;       // batch rows per WG  (grid = 256 = 1 WG/CU)
constexpr int AP = 72;      // Abuf row pitch in bf16 elems (144 B, 2-way free)
constexpr int T6 = T_ * I_; // floats per batch row of x

__global__ __launch_bounds__(512, 1)
void lstm_kernel(const float* __restrict__ x,
                 const float* __restrict__ W_ih, const float* __restrict__ W_hh,
                 const float* __restrict__ b_ih, const float* __restrict__ b_hh,
                 const float* __restrict__ W_out, const float* __restrict__ b_out,
                 float* __restrict__ out)
{
  __shared__ unsigned short Xpack[T_][NB][8];  // 64 KB: [x0..x5, 1.0, 0] bf16 per (t,b)
  __shared__ unsigned short Abuf[2][16 * AP];  // 4.6 KB: h at pos 0..47,56,57; rest 0
  __shared__ float Hlast[NB][H_];

  const int tid  = threadIdx.x;
  const int lane = tid & 63;
  const int wave = tid >> 6;
  const int col  = lane & 15;   // MFMA N index = batch row
  const int quad = lane >> 4;   // MFMA k-slice group
  const int b0   = blockIdx.x * NB;

  // ---- stage Xpack: thread tid handles (t=tid, b=i); consecutive tids read
  // consecutive 24 B chunks of row b0+i (coalesced). One-time, 96 KB in. ----
  #pragma unroll
  for (int i = 0; i < NB; i++) {
    const float* xp = x + (size_t)(b0 + i) * T6 + tid * I_;
    const float2 a0 = *(const float2*)(xp);
    const float2 a1 = *(const float2*)(xp + 2);
    const float2 a2 = *(const float2*)(xp + 4);
    unsigned* dst = (unsigned*)&Xpack[tid][i][0];
    dst[0] = (unsigned)f2bf(a0.x) | ((unsigned)f2bf(a0.y) << 16);
    dst[1] = (unsigned)f2bf(a1.x) | ((unsigned)f2bf(a1.y) << 16);
    dst[2] = (unsigned)f2bf(a2.x) | ((unsigned)f2bf(a2.y) << 16);
    dst[3] = 0x3F80u;            // [bias=1.0, 0]
  }

  // ---- zero Abuf (h(0)=0; pads stay 0 forever) ----
  for (int i = tid; i < 2 * 16 * AP; i += 512) (&Abuf[0][0])[i] = 0;

  // ---- load weight fragments (A-operand, once), PRE-SCALED by L2E ----
  // wave w owns tiles jt in {w, w+8} (jt<13). lane holds W' row jp = jt*16+col,
  // k'-slice quad*8..+7 (+32 for kh=1). jp = 4*hidx+gate -> src row = gate*50+hidx.
  // gate rows scaled by L2E (sigmoid) or 2*L2E (gate 2, tanh) so the
  // elementwise phase needs no per-gate multiply.
  // k' map: 0..47 -> W_hh[.][k'], 48..53 -> W_ih[.][k'-48], 54 -> bias,
  //         56,57 -> W_hh[.][48,49], else 0.
  const int ntw = (wave < 5) ? 2 : 1;   // tiles 0..12
  s16x8 wf[2][2];
  #pragma unroll
  for (int ti = 0; ti < 2; ti++) {
    if (ti < ntw) {
      const int jp = (wave + 8 * ti) * 16 + col;
      const bool ok = jp < 200;
      const int hidx = jp >> 2, g = jp & 3;
      const int row = g * 50 + hidx;
      const float scl = (g == 2) ? (2.0f * L2E) : L2E;
      #pragma unroll
      for (int kh = 0; kh < 2; kh++) {
        s16x8 w;
        #pragma unroll
        for (int kk = 0; kk < 8; kk++) {
          const int k = kh * 32 + quad * 8 + kk;
          float v = 0.0f;
          if (ok) {
            if      (k < 48)  v = W_hh[row * 50 + k];
            else if (k < 54)  v = W_ih[row * 6 + (k - 48)];
            else if (k == 54) v = b_ih[row] + b_hh[row];
            else if (k == 56) v = W_hh[row * 50 + 48];
            else if (k == 57) v = W_hh[row * 50 + 49];
          }
          w[kk] = (short)f2bf(v * scl);
        }
        wf[ti][kh] = w;
      }
    }
  }

  // ---- lane pair identity: b = col&7, hh = 4*(wave + 8*(col>=8)) + quad ----
  const int ti_r  = col >> 3;
  const int b_r   = col & 7;
  const int jt_r  = wave + 8 * ti_r;
  const int hh    = 4 * jt_r + quad;
  const bool valid = (jt_r < 13) && (hh < H_);
  const int pos   = hh + ((hh >= 48) ? 8 : 0);   // h48,h49 live at 56,57

  float c_ = 0.0f, hreg = 0.0f;

  __syncthreads();

  #pragma unroll 2
  for (int t = 0; t < T_; t++) {
    const unsigned short* Ar = &Abuf[t & 1][0];
    unsigned short*       Aw = &Abuf[(t + 1) & 1][0];

    // B-operand fragments: B[k'][n=batch]. quad2's kh=1 slice is [x|bias|0],
    // read straight from Xpack. cols 8..15 read zero rows (never written).
    const unsigned short* arow = Ar + col * AP;
    const s16x8 bfr0 = *(const s16x8*)(arow + quad * 8);
    const unsigned short* p1 = (quad == 2) ? &Xpack[t][b_r][0]
                                           : (arow + 32 + quad * 8);
    const s16x8 bfr1 = *(const s16x8*)p1;

    // MFMA: acc reg r = gate r of pair (b=col, hh=4*jt+quad)
    f32x4 a0 = {0.f, 0.f, 0.f, 0.f};
    a0 = __builtin_amdgcn_mfma_f32_16x16x32_bf16(wf[0][0], bfr0, a0, 0, 0, 0);
    a0 = __builtin_amdgcn_mfma_f32_16x16x32_bf16(wf[0][1], bfr1, a0, 0, 0, 0);
    f32x4 g = a0;
    if (wave < 5) {   // tile 1 exists: move its pairs to cols 8..15 via xor-8
      f32x4 a1 = {0.f, 0.f, 0.f, 0.f};
      a1 = __builtin_amdgcn_mfma_f32_16x16x32_bf16(wf[1][0], bfr0, a1, 0, 0, 0);
      a1 = __builtin_amdgcn_mfma_f32_16x16x32_bf16(wf[1][1], bfr1, a1, 0, 0, 0);
      #pragma unroll
      for (int r = 0; r < 4; r++) {
        const float o = __shfl_xor(a1[r], 8, 64);
        g[r] = (ti_r == 0) ? a0[r] : o;
      }
    }

    // elementwise: inputs pre-scaled by L2E (2*L2E for gate 2)
    if (valid) {
      const float gi = sigm_p(g[0]);
      const float gf = sigm_p(g[1]);
      const float gg = tanh_p(g[2]);
      const float go = sigm_p(g[3]);
      c_ = gf * c_ + gi * gg;
      hreg = go * tanh_p(c_ * (2.0f * L2E));
      Aw[b_r * AP + pos] = f2bf(hreg);
    }

    __syncthreads();  // Aw visible to all waves; lgkm-only drain (no vmcnt)
  }

  // ---- epilogue: logits + softmax ----
  if (valid) Hlast[b_r][hh] = hreg;
  __syncthreads();

  if (tid < NB) {
    float l[3];
    #pragma unroll
    for (int o = 0; o < 3; o++) {
      float s = b_out[o];
      for (int k = 0; k < H_; k++) s += W_out[o * H_ + k] * Hlast[tid][k];
      l[o] = s;
    }
    const float m  = fmaxf(l[0], fmaxf(l[1], l[2]));
    const float e0 = fast_exp2((l[0] - m) * L2E);
    const float e1 = fast_exp2((l[1] - m) * L2E);
    const float e2 = fast_exp2((l[2] - m) * L2E);
    const float inv = fast_rcp(e0 + e1 + e2);
    float* op = out + (size_t)(b0 + tid) * 3;
    op[0] = e0 * inv; op[1] = e1 * inv; op[2] = e2 * inv;
  }
}

extern "C" void kernel_launch(void* const* d_in, const int* in_sizes, int n_in,
                              void* d_out, int out_size, void* d_ws, size_t ws_size,
                              hipStream_t stream) {
  const float* x     = (const float*)d_in[0];
  const float* W_ih  = (const float*)d_in[1];
  const float* W_hh  = (const float*)d_in[2];
  const float* b_ih  = (const float*)d_in[3];
  const float* b_hh  = (const float*)d_in[4];
  const float* W_out = (const float*)d_in[5];
  const float* b_out = (const float*)d_in[6];
  lstm_kernel<<<B_ / NB, 512, 0, stream>>>(x, W_ih, W_hh, b_ih, b_hh,
                                           W_out, b_out, (float*)d_out);
}